// Round 13
// baseline (1774.332 us; speedup 1.0000x reference)
//
#include <hip/hip_runtime.h>
#include <math.h>

#define NN 33
#define NC 2112   // 33*64

typedef __attribute__((ext_vector_type(8))) short bfrag;
typedef __attribute__((ext_vector_type(4))) float f32x4;

// ---- ws float offsets ----
#define OFF_LT   0          // 33*68: L^T column-doubled  LTd[m][nn]=L[nn%33][m]
#define OFF_L2T  2244       // 33*68: (2*L@L)^T column-doubled
#define OFF_UP1  4488       // 24576 ushort: cheb1 fused U, split-bf16 B-frag blocks
#define OFF_UP2  16776      // cheb2
#define OFF_WT0  29064      // 73728 ushort: s1_tc2 split-bf16 MFMA layout
#define OFF_WT1  65928      // s2_tc1
#define OFF_WT2  102792     // s2_tc2
#define OFF_ST1  139656     // 66 floats
#define OFF_ST2  139722     // 66 floats
#define OFF_HB   139856     // 32*256 fc1 split-K accumulator
#define OFF_MEAN 148048     // 32*2112
#define OFF_A    215632     // big buffer: 32 * 508 * 2112 floats
#define A_ELEMS  34332672ull
#define SLAB     1077120ull // 510*2112 floats per b of scratch

__device__ inline unsigned short f2bf(float x) {
  unsigned int u = __float_as_uint(x);
  unsigned int r = (u + 0x7fffu + ((u >> 16) & 1u)) >> 16;
  return (unsigned short)r;
}
__device__ inline float bf2f(unsigned short h) {
  return __uint_as_float(((unsigned int)h) << 16);
}

// =====================================================================
// K0: weight prep (blocks 0..287) + Laplacian (block 288).
__global__ __launch_bounds__(256) void k_prep(
    const int* __restrict__ ei,
    const float* __restrict__ cw1, const float* __restrict__ cw2,
    const float* __restrict__ tw0, const float* __restrict__ tw1,
    const float* __restrict__ tw2, float* __restrict__ ws) {
  int tid = threadIdx.x;
  if (blockIdx.x == 288) {
    __shared__ float Lsm[1089];
    __shared__ float L2sm[1089];
    __shared__ float deg[NN];
    __shared__ float dinv[NN];
    for (int i = tid; i < 1089; i += 256) Lsm[i] = 0.f;
    if (tid < NN) deg[tid] = 0.f;
    __syncthreads();
    if (tid < 64) atomicAdd(&deg[ei[tid]], 1.f);
    __syncthreads();
    if (tid < NN) dinv[tid] = deg[tid] > 0.f ? rsqrtf(deg[tid]) : 0.f;
    __syncthreads();
    if (tid < 64) {
      int s = ei[tid], t = ei[64 + tid];
      atomicAdd(&Lsm[t * NN + s], -dinv[s] * dinv[t]);
    }
    __syncthreads();
    for (int i = tid; i < 1089; i += 256) {
      int r = i / NN, c = i % NN;
      float s = 0.f;
      for (int m = 0; m < NN; m++) s += Lsm[r * NN + m] * Lsm[m * NN + c];
      L2sm[i] = 2.f * s;
    }
    __syncthreads();
    for (int i = tid; i < 33 * 66; i += 256) {
      int m = i / 66, nn = i % 66;
      int n33 = nn < 33 ? nn : nn - 33;
      ws[OFF_LT + m * 68 + nn]  = Lsm[n33 * NN + m];
      ws[OFF_L2T + m * 68 + nn] = L2sm[n33 * NN + m];
    }
    return;
  }
  int u = blockIdx.x * 256 + tid;
  if (u < 24576) {
    unsigned short* u1 = (unsigned short*)(ws + OFF_UP1);
    unsigned short* u2 = (unsigned short*)(ws + OFF_UP2);
    int j = u & 7;
    int nn = (u >> 3) & 15;
    int q = (u >> 7) & 3;
    int sp = (u >> 9) & 1;
    int blk = u >> 10;
    int nt = blk & 3;
    int ks = blk >> 2;
    int k = ks * 32 + q * 8 + j;
    int d = nt * 16 + nn;
    int s = k >> 6, cc = k & 63;
    float v1 = cw1[(s * 64 + cc) * 64 + d];
    float v2 = cw2[(s * 64 + cc) * 64 + d];
    if (s == 0) { v1 -= cw1[(128 + cc) * 64 + d]; v2 -= cw2[(128 + cc) * 64 + d]; }
    unsigned short h1 = f2bf(v1);
    u1[u] = sp ? f2bf(v1 - bf2f(h1)) : h1;
    unsigned short h2 = f2bf(v2);
    u2[u] = sp ? f2bf(v2 - bf2f(h2)) : h2;
  }
  {
    unsigned short* p0 = (unsigned short*)(ws + OFF_WT0);
    unsigned short* p1 = (unsigned short*)(ws + OFF_WT1);
    unsigned short* p2 = (unsigned short*)(ws + OFF_WT2);
    int j  = u & 7;
    int nn_ = (u >> 3) & 15;
    int q  = (u >> 7) & 3;
    int B  = u >> 9;
    int sp = B & 1;
    int B2 = B >> 1;
    int nt = B2 % 12;
    int dk = B2 / 12;
    int ks = dk & 1;
    int dt = dk >> 1;
    int o  = nt * 16 + nn_;
    int ci = ks * 32 + q * 8 + j;
    int src = (o * 64 + ci) * 3 + dt;
    float w0 = tw0[src], w1 = tw1[src], w2 = tw2[src];
    unsigned short h;
    h = f2bf(w0); p0[u] = sp ? f2bf(w0 - bf2f(h)) : h;
    h = f2bf(w1); p1[u] = sp ? f2bf(w1 - bf2f(h)) : h;
    h = f2bf(w2); p2[u] = sp ? f2bf(w2 - bf2f(h)) : h;
  }
}

// =====================================================================
// K1: small gated tconv (Ci=3), x -> HS  (chunk slabs, stride 510 rows)
__global__ __launch_bounds__(256) void k_tconv0(
    const float* __restrict__ x, const float* __restrict__ w,
    const float* __restrict__ bias, float* __restrict__ out,
    int b0, int total) {
  __shared__ float wsm[1728];
  __shared__ float bsm[192];
  int tid = threadIdx.x;
  for (int i = tid; i < 1728; i += 256) wsm[i] = w[i];
  if (tid < 192) bsm[tid] = bias[tid];
  __syncthreads();
  int idx = blockIdx.x * 256 + tid;
  if (idx >= total) return;
  int ch = idx & 63;
  int r = idx >> 6;
  int n = r % NN; r /= NN;
  int t = r % 510;
  int bc = r / 510;
  int b = b0 + bc;
  float aP = bsm[ch], aQ = bsm[64 + ch], aR = bsm[128 + ch];
  const float* xp = x + ((size_t)(b * 512 + t) * NN + n) * 3;
  #pragma unroll
  for (int dt = 0; dt < 3; dt++) {
    float x0 = xp[dt * 99 + 0], x1 = xp[dt * 99 + 1], x2 = xp[dt * 99 + 2];
    aP += x0 * wsm[(ch * 3 + 0) * 3 + dt] + x1 * wsm[(ch * 3 + 1) * 3 + dt] + x2 * wsm[(ch * 3 + 2) * 3 + dt];
    aQ += x0 * wsm[((64 + ch) * 3 + 0) * 3 + dt] + x1 * wsm[((64 + ch) * 3 + 1) * 3 + dt] + x2 * wsm[((64 + ch) * 3 + 2) * 3 + dt];
    aR += x0 * wsm[((128 + ch) * 3 + 0) * 3 + dt] + x1 * wsm[((128 + ch) * 3 + 1) * 3 + dt] + x2 * wsm[((128 + ch) * 3 + 2) * 3 + dt];
  }
  float sg = 1.f / (1.f + __expf(-aQ));
  out[(size_t)(bc * 510 + t) * NC + n * 64 + ch] = fmaxf(aP * sg + aR, 0.f);
}

// =====================================================================
// K2: fused ChebConv, barrier-free, software-pipelined U loads (R10).
__global__ __launch_bounds__(256, 4) void k_chebmm(
    const float* __restrict__ in, const unsigned short* __restrict__ Uf,
    const float* __restrict__ cbias, float* __restrict__ out,
    const float* __restrict__ ws, int totalRows) {
  __shared__ __attribute__((aligned(16))) unsigned short Zh[64 * 136];
  __shared__ __attribute__((aligned(16))) unsigned short Zl[64 * 136];

  int tid = threadIdx.x;
  int R0 = blockIdx.x * 64;
  int c = tid & 63;
  int g = __builtin_amdgcn_readfirstlane(tid >> 6);
  int Rg = R0 + g * 16;
  int btg = Rg / 33;
  int n0 = Rg - btg * 33;
  int wrap = 33 - n0;

  const float* lt  = ws + OFF_LT;
  const float* l2t = ws + OFF_L2T;
  const float* ipA = in + (size_t)btg * NC + c;
  const float* ipB = ipA + NC;
  float z1[16], z2[16];
  #pragma unroll
  for (int rr = 0; rr < 16; rr++) { z1[rr] = 0.f; z2[rr] = 0.f; }
  #pragma unroll 3
  for (int m = 0; m < NN; m++) {
    float hvA = ipA[m * 64];
    float hvB = ipB[m * 64];
    const float* ltm  = lt + m * 68 + n0;
    const float* l2tm = l2t + m * 68 + n0;
    #pragma unroll
    for (int rr = 0; rr < 16; rr++) {
      float hv = (rr < wrap) ? hvA : hvB;
      z1[rr] += ltm[rr] * hv;
      z2[rr] += l2tm[rr] * hv;
    }
  }
  #pragma unroll
  for (int rr = 0; rr < 16; rr++) {
    int r = g * 16 + rr;
    unsigned short zh1 = f2bf(z1[rr]);
    Zh[r * 136 + c] = zh1;
    Zl[r * 136 + c] = f2bf(z1[rr] - bf2f(zh1));
    unsigned short zh2 = f2bf(z2[rr]);
    Zh[r * 136 + 64 + c] = zh2;
    Zl[r * 136 + 64 + c] = f2bf(z2[rr] - bf2f(zh2));
  }

  int lane = tid & 63;
  int m15 = lane & 15, q = lane >> 4;
  f32x4 acc[4];
  #pragma unroll
  for (int nt = 0; nt < 4; nt++) acc[nt] = (f32x4){0.f, 0.f, 0.f, 0.f};

  const float* hrow = in + (size_t)(Rg + m15) * 64 + q * 8;
  float hv0[8], hv1[8];
  *(float4*)&hv0[0] = *(const float4*)(hrow);
  *(float4*)&hv0[4] = *(const float4*)(hrow + 4);
  *(float4*)&hv1[0] = *(const float4*)(hrow + 32);
  *(float4*)&hv1[4] = *(const float4*)(hrow + 36);

  bfrag uh[4], ul[4];
  #pragma unroll
  for (int nt = 0; nt < 4; nt++) {
    const unsigned short* bp = Uf + nt * 1024 + lane * 8;
    uh[nt] = *(const bfrag*)bp;
    ul[nt] = *(const bfrag*)(bp + 512);
  }

  #pragma unroll
  for (int ks = 0; ks < 6; ks++) {
    bfrag nh[4], nl[4];
    if (ks < 5) {
      #pragma unroll
      for (int nt = 0; nt < 4; nt++) {
        const unsigned short* bp = Uf + ((ks + 1) * 4 + nt) * 1024 + lane * 8;
        nh[nt] = *(const bfrag*)bp;
        nl[nt] = *(const bfrag*)(bp + 512);
      }
    }
    bfrag ah, al;
    if (ks < 2) {
      const float* hv = (ks == 0) ? hv0 : hv1;
      union { bfrag v; unsigned short s[8]; } Ahf, Alf;
      #pragma unroll
      for (int j = 0; j < 8; j++) {
        unsigned short hh = f2bf(hv[j]);
        Ahf.s[j] = hh;
        Alf.s[j] = f2bf(hv[j] - bf2f(hh));
      }
      ah = Ahf.v; al = Alf.v;
    } else {
      int aoff = (g * 16 + m15) * 136 + (ks - 2) * 32 + q * 8;
      ah = *(const bfrag*)(Zh + aoff);
      al = *(const bfrag*)(Zl + aoff);
    }
    #pragma unroll
    for (int nt = 0; nt < 4; nt++) {
      acc[nt] = __builtin_amdgcn_mfma_f32_16x16x32_bf16(ah, uh[nt], acc[nt], 0, 0, 0);
      acc[nt] = __builtin_amdgcn_mfma_f32_16x16x32_bf16(ah, ul[nt], acc[nt], 0, 0, 0);
      acc[nt] = __builtin_amdgcn_mfma_f32_16x16x32_bf16(al, uh[nt], acc[nt], 0, 0, 0);
    }
    #pragma unroll
    for (int nt = 0; nt < 4; nt++) { uh[nt] = nh[nt]; ul[nt] = nl[nt]; }
  }
  #pragma unroll
  for (int nt = 0; nt < 4; nt++) {
    int d = nt * 16 + m15;
    float bd = cbias[d];
    #pragma unroll
    for (int rr = 0; rr < 4; rr++) {
      int R = R0 + g * 16 + q * 4 + rr;
      if (R < totalRows)
        out[(size_t)R * 64 + d] = fmaxf(acc[nt][rr] + bd, 0.f);
    }
  }
}

// =====================================================================
// K3 v12: gated tconv, M=64, wave = 16-channel quadrant (R10 v9 base)
// + CROSS-STEP B-frag prefetch pipeline (chebmm-style): loads for step
// s+1 issue before step s's MFMAs, hiding ~300-cyc L2 latency.
__global__ __launch_bounds__(256, 4) void k_tconv(
    const float* __restrict__ in, int inStride, int Tin,
    const unsigned short* __restrict__ wsp, const float* __restrict__ bias,
    float* __restrict__ out, int outStride, int Tout,
    const float* __restrict__ bnSt, const float* __restrict__ bnG,
    const float* __restrict__ bnB, float bnCnt, float* __restrict__ statsOut) {
  __shared__ __attribute__((aligned(16))) unsigned short Ah[66 * 72];
  __shared__ __attribute__((aligned(16))) unsigned short Al[66 * 72];
  int tid = threadIdx.x;
  int ntt = (Tout + 63) >> 6;
  int tpb = NN * ntt;
  int bc = blockIdx.x / tpb, r = blockIdx.x % tpb;
  int n = r / ntt, tt = r % ntt;
  int t0 = tt << 6;
  const float* ip = in + (size_t)bc * inStride * NC + n * 64;

  float sc = 1.f, sh = 0.f;
  if (bnSt) {
    float mean = bnSt[n] / bnCnt;
    float var = bnSt[33 + n] / bnCnt - mean * mean;
    sc = rsqrtf(var + 1e-5f) * bnG[n];
    sh = bnB[n] - mean * sc;
  }
  for (int i = tid; i < 66 * 16; i += 256) {
    int row = i >> 4, c4 = i & 15;
    float4 v = make_float4(0.f, 0.f, 0.f, 0.f);
    if (t0 + row < Tin) v = *(const float4*)(ip + (size_t)(t0 + row) * NC + c4 * 4);
    if (bnSt) {
      v.x = fmaxf(v.x * sc + sh, 0.f);
      v.y = fmaxf(v.y * sc + sh, 0.f);
      v.z = fmaxf(v.z * sc + sh, 0.f);
      v.w = fmaxf(v.w * sc + sh, 0.f);
    }
    unsigned short h0 = f2bf(v.x), h1 = f2bf(v.y), h2 = f2bf(v.z), h3 = f2bf(v.w);
    unsigned short l0 = f2bf(v.x - bf2f(h0)), l1 = f2bf(v.y - bf2f(h1));
    unsigned short l2 = f2bf(v.z - bf2f(h2)), l3 = f2bf(v.w - bf2f(h3));
    uint2 ph, pl;
    ph.x = (unsigned)h0 | ((unsigned)h1 << 16); ph.y = (unsigned)h2 | ((unsigned)h3 << 16);
    pl.x = (unsigned)l0 | ((unsigned)l1 << 16); pl.y = (unsigned)l2 | ((unsigned)l3 << 16);
    *(uint2*)(Ah + row * 72 + c4 * 4) = ph;
    *(uint2*)(Al + row * 72 + c4 * 4) = pl;
  }
  __syncthreads();

  int lane = tid & 63;
  int wv = tid >> 6;          // channel quadrant
  int m15 = lane & 15, q = lane >> 4;

  f32x4 acc[4][3];            // acc[mi][gate]
  #pragma unroll
  for (int mi = 0; mi < 4; mi++)
    #pragma unroll
    for (int j = 0; j < 3; j++) acc[mi][j] = (f32x4){0.f, 0.f, 0.f, 0.f};

  // prefetch B for step 0
  bfrag bh[3], bl[3];
  #pragma unroll
  for (int j = 0; j < 3; j++) {
    int nt = wv + 4 * j;
    const unsigned short* bp = wsp + ((0 * 12 + nt) * 2) * 512 + lane * 8;
    bh[j] = *(const bfrag*)bp;
    bl[j] = *(const bfrag*)(bp + 512);
  }

  #pragma unroll
  for (int s = 0; s < 6; s++) {
    int dt = s >> 1, ks = s & 1;
    // prefetch B for step s+1 (in flight across this step's MFMAs)
    bfrag nh[3], nl[3];
    if (s < 5) {
      int dt1 = (s + 1) >> 1, ks1 = (s + 1) & 1;
      const unsigned short* wdt1 = wsp + (size_t)dt1 * 24576;
      #pragma unroll
      for (int j = 0; j < 3; j++) {
        int nt = wv + 4 * j;
        const unsigned short* bp = wdt1 + ((ks1 * 12 + nt) * 2) * 512 + lane * 8;
        nh[j] = *(const bfrag*)bp;
        nl[j] = *(const bfrag*)(bp + 512);
      }
    }
    bfrag ah[4], al[4];
    #pragma unroll
    for (int mi = 0; mi < 4; mi++) {
      int row = mi * 16 + m15 + dt;
      int off = row * 72 + ks * 32 + q * 8;
      ah[mi] = *(const bfrag*)(Ah + off);
      al[mi] = *(const bfrag*)(Al + off);
    }
    #pragma unroll
    for (int j = 0; j < 3; j++)
      #pragma unroll
      for (int mi = 0; mi < 4; mi++) {
        acc[mi][j] = __builtin_amdgcn_mfma_f32_16x16x32_bf16(ah[mi], bh[j], acc[mi][j], 0, 0, 0);
        acc[mi][j] = __builtin_amdgcn_mfma_f32_16x16x32_bf16(ah[mi], bl[j], acc[mi][j], 0, 0, 0);
        acc[mi][j] = __builtin_amdgcn_mfma_f32_16x16x32_bf16(al[mi], bh[j], acc[mi][j], 0, 0, 0);
      }
    #pragma unroll
    for (int j = 0; j < 3; j++) { bh[j] = nh[j]; bl[j] = nl[j]; }
  }

  float ssum = 0.f, sq = 0.f;
  int ch = wv * 16 + m15;
  float bP = bias[ch], bQ = bias[64 + ch], bR = bias[128 + ch];
  #pragma unroll
  for (int mi = 0; mi < 4; mi++) {
    #pragma unroll
    for (int rr = 0; rr < 4; rr++) {
      int t = t0 + mi * 16 + q * 4 + rr;
      float P = acc[mi][0][rr] + bP;
      float Q = acc[mi][1][rr] + bQ;
      float Rv = acc[mi][2][rr] + bR;
      float sg = 1.f / (1.f + __expf(-Q));
      float h = fmaxf(P * sg + Rv, 0.f);
      if (t < Tout) {
        out[(size_t)(bc * outStride + t) * NC + n * 64 + ch] = h;
        ssum += h; sq += h * h;
      }
    }
  }
  if (statsOut) {
    #pragma unroll
    for (int d = 32; d > 0; d >>= 1) {
      ssum += __shfl_down(ssum, d);
      sq += __shfl_down(sq, d);
    }
    if (lane == 0) {
      atomicAdd(&statsOut[n], ssum);
      atomicAdd(&statsOut[33 + n], sq);
    }
  }
}

// =====================================================================
// K5b: BN apply + relu + mean over T (stage 2), no materialization.
__global__ __launch_bounds__(256) void k_bnmean(
    const float* __restrict__ A, int stride, int Tv,
    const float* __restrict__ st, const float* __restrict__ gg,
    const float* __restrict__ bb, float* __restrict__ mout) {
  int idx = blockIdx.x * 256 + threadIdx.x;   // 32*2112
  int p = idx % NC, b = idx / NC;
  int n = p >> 6;
  float cnt = (float)(32 * Tv * 64);
  float mean = st[n] / cnt;
  float var = st[33 + n] / cnt - mean * mean;
  float sc = rsqrtf(var + 1e-5f) * gg[n];
  float sh = bb[n] - mean * sc;
  float acc = 0.f;
  const float* ap = A + (size_t)b * stride * NC + p;
  for (int t = 0; t < Tv; t += 4) {
    acc += fmaxf(ap[(size_t)t * NC] * sc + sh, 0.f)
         + fmaxf(ap[(size_t)(t + 1) * NC] * sc + sh, 0.f)
         + fmaxf(ap[(size_t)(t + 2) * NC] * sc + sh, 0.f)
         + fmaxf(ap[(size_t)(t + 3) * NC] * sc + sh, 0.f);
  }
  mout[idx] = acc / (float)Tv;
}

// K6a: fc1 split-K.  Grid 256 = (b 32) x (ks 8); thread = out-dim d.
__global__ __launch_bounds__(256) void k_fc1(
    const float* __restrict__ meanb, const float* __restrict__ w1,
    float* __restrict__ hb) {
  int b = blockIdx.x >> 3, ks = blockIdx.x & 7;
  int d = threadIdx.x;
  const float* mp = meanb + b * NC + ks * 264;
  const float* wp = w1 + (size_t)(ks * 264) * 256 + d;
  float acc = 0.f;
  for (int k = 0; k < 264; k += 8) {
    #pragma unroll
    for (int u = 0; u < 8; u++)
      acc += mp[k + u] * wp[(size_t)(k + u) * 256];
  }
  atomicAdd(&hb[b * 256 + d], acc);
}

// K6b: relu(h+b1) then fc2.  One block per batch sample.
__global__ __launch_bounds__(256) void k_fc2(
    const float* __restrict__ hb, const float* __restrict__ b1,
    const float* __restrict__ w2, const float* __restrict__ b2,
    float* __restrict__ out) {
  __shared__ float h[256];
  int tid = threadIdx.x, b = blockIdx.x;
  h[tid] = fmaxf(hb[b * 256 + tid] + b1[tid], 0.f);
  __syncthreads();
  if (tid < 10) {
    float a = b2[tid];
    for (int k = 0; k < 256; k++) a += h[k] * w2[k * 10 + tid];
    out[b * 10 + tid] = a;
  }
}

// =====================================================================
extern "C" void kernel_launch(void* const* d_in, const int* in_sizes, int n_in,
                              void* d_out, int out_size, void* d_ws, size_t ws_size,
                              hipStream_t stream) {
  const float* x        = (const float*)d_in[0];
  const int*   ei       = (const int*)d_in[1];
  const float* s1_tc1_w = (const float*)d_in[2];
  const float* s1_tc1_b = (const float*)d_in[3];
  const float* s1_cheb_w= (const float*)d_in[4];
  const float* s1_cheb_b= (const float*)d_in[5];
  const float* s1_tc2_w = (const float*)d_in[6];
  const float* s1_tc2_b = (const float*)d_in[7];
  const float* s1_bn_g  = (const float*)d_in[8];
  const float* s1_bn_b  = (const float*)d_in[9];
  const float* s2_tc1_w = (const float*)d_in[10];
  const float* s2_tc1_b = (const float*)d_in[11];
  const float* s2_cheb_w= (const float*)d_in[12];
  const float* s2_cheb_b= (const float*)d_in[13];
  const float* s2_tc2_w = (const float*)d_in[14];
  const float* s2_tc2_b = (const float*)d_in[15];
  const float* s2_bn_g  = (const float*)d_in[16];
  const float* s2_bn_b  = (const float*)d_in[17];
  const float* fc1_w    = (const float*)d_in[18];
  const float* fc1_b    = (const float*)d_in[19];
  const float* fc2_w    = (const float*)d_in[20];
  const float* fc2_b    = (const float*)d_in[21];
  float* ws  = (float*)d_ws;
  float* out = (float*)d_out;

  int chunk = 8;
  while (chunk > 1 &&
         ((size_t)OFF_A + A_ELEMS + (size_t)chunk * SLAB * 2) * 4 > ws_size)
    chunk >>= 1;
  float* A  = ws + OFF_A;
  float* HS = A + A_ELEMS;
  float* CS = HS + (size_t)chunk * SLAB;

  hipMemsetAsync(ws + OFF_ST1, 0, (OFF_HB + 8192 - OFF_ST1) * sizeof(float), stream);
  k_prep<<<289, 256, 0, stream>>>(ei, s1_cheb_w, s2_cheb_w,
                                  s1_tc2_w, s2_tc1_w, s2_tc2_w, ws);

  const unsigned short* wt0 = (const unsigned short*)(ws + OFF_WT0);
  const unsigned short* wt1 = (const unsigned short*)(ws + OFF_WT1);
  const unsigned short* wt2 = (const unsigned short*)(ws + OFF_WT2);
  const unsigned short* uf1 = (const unsigned short*)(ws + OFF_UP1);
  const unsigned short* uf2 = (const unsigned short*)(ws + OFF_UP2);

  int nchunks = 32 / chunk;
  int rowsC = chunk * 510 * NN;
  int nblkC = (rowsC + 63) / 64;
  float cnt1 = (float)(32 * 508 * 64);
  // ---------------- stage 1 ----------------
  for (int ci = 0; ci < nchunks; ci++) {
    int b0 = ci * chunk;
    int total0 = chunk * 510 * NC;
    k_tconv0<<<(total0 + 255) / 256, 256, 0, stream>>>(x, s1_tc1_w, s1_tc1_b,
                                                       HS, b0, total0);
    k_chebmm<<<nblkC, 256, 0, stream>>>(HS, uf1, s1_cheb_b, CS, ws, rowsC);
    k_tconv<<<chunk * NN * 8, 256, 0, stream>>>(CS, 510, 510, wt0, s1_tc2_b,
                                                A + (size_t)b0 * 508 * NC, 508, 508,
                                                nullptr, nullptr, nullptr, 1.f,
                                                ws + OFF_ST1);
  }
  // ---------------- stage 2 ----------------
  for (int ci = 0; ci < nchunks; ci++) {
    int b0 = ci * chunk;
    k_tconv<<<chunk * NN * 8, 256, 0, stream>>>(A + (size_t)b0 * 508 * NC, 508, 508,
                                                wt1, s2_tc1_b, HS, 510, 506,
                                                ws + OFF_ST1, s1_bn_g, s1_bn_b, cnt1,
                                                nullptr);
    k_chebmm<<<nblkC, 256, 0, stream>>>(HS, uf2, s2_cheb_b, CS, ws, rowsC);
    k_tconv<<<chunk * NN * 8, 256, 0, stream>>>(CS, 510, 506, wt2, s2_tc2_b,
                                                A + (size_t)b0 * 508 * NC, 508, 504,
                                                nullptr, nullptr, nullptr, 1.f,
                                                ws + OFF_ST2);
  }
  k_bnmean<<<(32 * NC) / 256, 256, 0, stream>>>(A, 508, 504, ws + OFF_ST2,
                                                s2_bn_g, s2_bn_b, ws + OFF_MEAN);
  k_fc1<<<256, 256, 0, stream>>>(ws + OFF_MEAN, fc1_w, ws + OFF_HB);
  k_fc2<<<32, 256, 0, stream>>>(ws + OFF_HB, fc1_b, fc2_w, fc2_b, out);
}

// Round 14
// 1287.100 us; speedup vs baseline: 1.3786x; 1.3786x over previous
//
#include <hip/hip_runtime.h>
#include <math.h>

#define NN 33
#define NC 2112   // 33*64

typedef __attribute__((ext_vector_type(8))) short bfrag;
typedef __attribute__((ext_vector_type(4))) float f32x4;

// ---- ws float offsets ----
#define OFF_LT   0          // 33*68: L^T column-doubled  LTd[m][nn]=L[nn%33][m]
#define OFF_L2T  2244       // 33*68: (2*L@L)^T column-doubled
#define OFF_UP1  4488       // 24576 ushort: cheb1 fused U, split-bf16 B-frag blocks
#define OFF_UP2  16776      // cheb2
#define OFF_WT0  29064      // 73728 ushort: s1_tc2 split-bf16 MFMA layout
#define OFF_WT1  65928      // s2_tc1
#define OFF_WT2  102792     // s2_tc2
#define OFF_ST1  139656     // 66 floats
#define OFF_ST2  139722     // 66 floats
#define OFF_HB   139856     // 32*256 fc1 split-K accumulator
#define OFF_MEAN 148048     // 32*2112
#define OFF_A    215632     // big buffer: 32 * 508 * 2112 floats
#define A_ELEMS  34332672ull
#define SLAB     1077120ull // 510*2112 floats per b of scratch

__device__ inline unsigned short f2bf(float x) {
  unsigned int u = __float_as_uint(x);
  unsigned int r = (u + 0x7fffu + ((u >> 16) & 1u)) >> 16;
  return (unsigned short)r;
}
__device__ inline float bf2f(unsigned short h) {
  return __uint_as_float(((unsigned int)h) << 16);
}

// =====================================================================
// K0: weight prep (blocks 0..287) + Laplacian (block 288).
__global__ __launch_bounds__(256) void k_prep(
    const int* __restrict__ ei,
    const float* __restrict__ cw1, const float* __restrict__ cw2,
    const float* __restrict__ tw0, const float* __restrict__ tw1,
    const float* __restrict__ tw2, float* __restrict__ ws) {
  int tid = threadIdx.x;
  if (blockIdx.x == 288) {
    __shared__ float Lsm[1089];
    __shared__ float L2sm[1089];
    __shared__ float deg[NN];
    __shared__ float dinv[NN];
    for (int i = tid; i < 1089; i += 256) Lsm[i] = 0.f;
    if (tid < NN) deg[tid] = 0.f;
    __syncthreads();
    if (tid < 64) atomicAdd(&deg[ei[tid]], 1.f);
    __syncthreads();
    if (tid < NN) dinv[tid] = deg[tid] > 0.f ? rsqrtf(deg[tid]) : 0.f;
    __syncthreads();
    if (tid < 64) {
      int s = ei[tid], t = ei[64 + tid];
      atomicAdd(&Lsm[t * NN + s], -dinv[s] * dinv[t]);
    }
    __syncthreads();
    for (int i = tid; i < 1089; i += 256) {
      int r = i / NN, c = i % NN;
      float s = 0.f;
      for (int m = 0; m < NN; m++) s += Lsm[r * NN + m] * Lsm[m * NN + c];
      L2sm[i] = 2.f * s;
    }
    __syncthreads();
    for (int i = tid; i < 33 * 66; i += 256) {
      int m = i / 66, nn = i % 66;
      int n33 = nn < 33 ? nn : nn - 33;
      ws[OFF_LT + m * 68 + nn]  = Lsm[n33 * NN + m];
      ws[OFF_L2T + m * 68 + nn] = L2sm[n33 * NN + m];
    }
    return;
  }
  int u = blockIdx.x * 256 + tid;
  if (u < 24576) {
    unsigned short* u1 = (unsigned short*)(ws + OFF_UP1);
    unsigned short* u2 = (unsigned short*)(ws + OFF_UP2);
    int j = u & 7;
    int nn = (u >> 3) & 15;
    int q = (u >> 7) & 3;
    int sp = (u >> 9) & 1;
    int blk = u >> 10;
    int nt = blk & 3;
    int ks = blk >> 2;
    int k = ks * 32 + q * 8 + j;
    int d = nt * 16 + nn;
    int s = k >> 6, cc = k & 63;
    float v1 = cw1[(s * 64 + cc) * 64 + d];
    float v2 = cw2[(s * 64 + cc) * 64 + d];
    if (s == 0) { v1 -= cw1[(128 + cc) * 64 + d]; v2 -= cw2[(128 + cc) * 64 + d]; }
    unsigned short h1 = f2bf(v1);
    u1[u] = sp ? f2bf(v1 - bf2f(h1)) : h1;
    unsigned short h2 = f2bf(v2);
    u2[u] = sp ? f2bf(v2 - bf2f(h2)) : h2;
  }
  {
    unsigned short* p0 = (unsigned short*)(ws + OFF_WT0);
    unsigned short* p1 = (unsigned short*)(ws + OFF_WT1);
    unsigned short* p2 = (unsigned short*)(ws + OFF_WT2);
    int j  = u & 7;
    int nn_ = (u >> 3) & 15;
    int q  = (u >> 7) & 3;
    int B  = u >> 9;
    int sp = B & 1;
    int B2 = B >> 1;
    int nt = B2 % 12;
    int dk = B2 / 12;
    int ks = dk & 1;
    int dt = dk >> 1;
    int o  = nt * 16 + nn_;
    int ci = ks * 32 + q * 8 + j;
    int src = (o * 64 + ci) * 3 + dt;
    float w0 = tw0[src], w1 = tw1[src], w2 = tw2[src];
    unsigned short h;
    h = f2bf(w0); p0[u] = sp ? f2bf(w0 - bf2f(h)) : h;
    h = f2bf(w1); p1[u] = sp ? f2bf(w1 - bf2f(h)) : h;
    h = f2bf(w2); p2[u] = sp ? f2bf(w2 - bf2f(h)) : h;
  }
}

// =====================================================================
// K1: small gated tconv (Ci=3), x -> HS  (chunk slabs, stride 510 rows)
__global__ __launch_bounds__(256) void k_tconv0(
    const float* __restrict__ x, const float* __restrict__ w,
    const float* __restrict__ bias, float* __restrict__ out,
    int b0, int total) {
  __shared__ float wsm[1728];
  __shared__ float bsm[192];
  int tid = threadIdx.x;
  for (int i = tid; i < 1728; i += 256) wsm[i] = w[i];
  if (tid < 192) bsm[tid] = bias[tid];
  __syncthreads();
  int idx = blockIdx.x * 256 + tid;
  if (idx >= total) return;
  int ch = idx & 63;
  int r = idx >> 6;
  int n = r % NN; r /= NN;
  int t = r % 510;
  int bc = r / 510;
  int b = b0 + bc;
  float aP = bsm[ch], aQ = bsm[64 + ch], aR = bsm[128 + ch];
  const float* xp = x + ((size_t)(b * 512 + t) * NN + n) * 3;
  #pragma unroll
  for (int dt = 0; dt < 3; dt++) {
    float x0 = xp[dt * 99 + 0], x1 = xp[dt * 99 + 1], x2 = xp[dt * 99 + 2];
    aP += x0 * wsm[(ch * 3 + 0) * 3 + dt] + x1 * wsm[(ch * 3 + 1) * 3 + dt] + x2 * wsm[(ch * 3 + 2) * 3 + dt];
    aQ += x0 * wsm[((64 + ch) * 3 + 0) * 3 + dt] + x1 * wsm[((64 + ch) * 3 + 1) * 3 + dt] + x2 * wsm[((64 + ch) * 3 + 2) * 3 + dt];
    aR += x0 * wsm[((128 + ch) * 3 + 0) * 3 + dt] + x1 * wsm[((128 + ch) * 3 + 1) * 3 + dt] + x2 * wsm[((128 + ch) * 3 + 2) * 3 + dt];
  }
  float sg = 1.f / (1.f + __expf(-aQ));
  out[(size_t)(bc * 510 + t) * NC + n * 64 + ch] = fmaxf(aP * sg + aR, 0.f);
}

// =====================================================================
// K2: fused ChebConv, barrier-free, software-pipelined U loads (R10).
__global__ __launch_bounds__(256, 4) void k_chebmm(
    const float* __restrict__ in, const unsigned short* __restrict__ Uf,
    const float* __restrict__ cbias, float* __restrict__ out,
    const float* __restrict__ ws, int totalRows) {
  __shared__ __attribute__((aligned(16))) unsigned short Zh[64 * 136];
  __shared__ __attribute__((aligned(16))) unsigned short Zl[64 * 136];

  int tid = threadIdx.x;
  int R0 = blockIdx.x * 64;
  int c = tid & 63;
  int g = __builtin_amdgcn_readfirstlane(tid >> 6);
  int Rg = R0 + g * 16;
  int btg = Rg / 33;
  int n0 = Rg - btg * 33;
  int wrap = 33 - n0;

  const float* lt  = ws + OFF_LT;
  const float* l2t = ws + OFF_L2T;
  const float* ipA = in + (size_t)btg * NC + c;
  const float* ipB = ipA + NC;
  float z1[16], z2[16];
  #pragma unroll
  for (int rr = 0; rr < 16; rr++) { z1[rr] = 0.f; z2[rr] = 0.f; }
  #pragma unroll 3
  for (int m = 0; m < NN; m++) {
    float hvA = ipA[m * 64];
    float hvB = ipB[m * 64];
    const float* ltm  = lt + m * 68 + n0;
    const float* l2tm = l2t + m * 68 + n0;
    #pragma unroll
    for (int rr = 0; rr < 16; rr++) {
      float hv = (rr < wrap) ? hvA : hvB;
      z1[rr] += ltm[rr] * hv;
      z2[rr] += l2tm[rr] * hv;
    }
  }
  #pragma unroll
  for (int rr = 0; rr < 16; rr++) {
    int r = g * 16 + rr;
    unsigned short zh1 = f2bf(z1[rr]);
    Zh[r * 136 + c] = zh1;
    Zl[r * 136 + c] = f2bf(z1[rr] - bf2f(zh1));
    unsigned short zh2 = f2bf(z2[rr]);
    Zh[r * 136 + 64 + c] = zh2;
    Zl[r * 136 + 64 + c] = f2bf(z2[rr] - bf2f(zh2));
  }

  int lane = tid & 63;
  int m15 = lane & 15, q = lane >> 4;
  f32x4 acc[4];
  #pragma unroll
  for (int nt = 0; nt < 4; nt++) acc[nt] = (f32x4){0.f, 0.f, 0.f, 0.f};

  const float* hrow = in + (size_t)(Rg + m15) * 64 + q * 8;
  float hv0[8], hv1[8];
  *(float4*)&hv0[0] = *(const float4*)(hrow);
  *(float4*)&hv0[4] = *(const float4*)(hrow + 4);
  *(float4*)&hv1[0] = *(const float4*)(hrow + 32);
  *(float4*)&hv1[4] = *(const float4*)(hrow + 36);

  bfrag uh[4], ul[4];
  #pragma unroll
  for (int nt = 0; nt < 4; nt++) {
    const unsigned short* bp = Uf + nt * 1024 + lane * 8;
    uh[nt] = *(const bfrag*)bp;
    ul[nt] = *(const bfrag*)(bp + 512);
  }

  #pragma unroll
  for (int ks = 0; ks < 6; ks++) {
    bfrag nh[4], nl[4];
    if (ks < 5) {
      #pragma unroll
      for (int nt = 0; nt < 4; nt++) {
        const unsigned short* bp = Uf + ((ks + 1) * 4 + nt) * 1024 + lane * 8;
        nh[nt] = *(const bfrag*)bp;
        nl[nt] = *(const bfrag*)(bp + 512);
      }
    }
    bfrag ah, al;
    if (ks < 2) {
      const float* hv = (ks == 0) ? hv0 : hv1;
      union { bfrag v; unsigned short s[8]; } Ahf, Alf;
      #pragma unroll
      for (int j = 0; j < 8; j++) {
        unsigned short hh = f2bf(hv[j]);
        Ahf.s[j] = hh;
        Alf.s[j] = f2bf(hv[j] - bf2f(hh));
      }
      ah = Ahf.v; al = Alf.v;
    } else {
      int aoff = (g * 16 + m15) * 136 + (ks - 2) * 32 + q * 8;
      ah = *(const bfrag*)(Zh + aoff);
      al = *(const bfrag*)(Zl + aoff);
    }
    #pragma unroll
    for (int nt = 0; nt < 4; nt++) {
      acc[nt] = __builtin_amdgcn_mfma_f32_16x16x32_bf16(ah, uh[nt], acc[nt], 0, 0, 0);
      acc[nt] = __builtin_amdgcn_mfma_f32_16x16x32_bf16(ah, ul[nt], acc[nt], 0, 0, 0);
      acc[nt] = __builtin_amdgcn_mfma_f32_16x16x32_bf16(al, uh[nt], acc[nt], 0, 0, 0);
    }
    #pragma unroll
    for (int nt = 0; nt < 4; nt++) { uh[nt] = nh[nt]; ul[nt] = nl[nt]; }
  }
  #pragma unroll
  for (int nt = 0; nt < 4; nt++) {
    int d = nt * 16 + m15;
    float bd = cbias[d];
    #pragma unroll
    for (int rr = 0; rr < 4; rr++) {
      int R = R0 + g * 16 + q * 4 + rr;
      if (R < totalRows)
        out[(size_t)R * 64 + d] = fmaxf(acc[nt][rr] + bd, 0.f);
    }
  }
}

// =====================================================================
// K3 (R10 v9, measured 63 us): gated tconv, M=64 block tile; wave =
// 16-channel quadrant over all 64 rows.  Per step: 3 B-frag pairs feed
// 36 MFMAs.  B from global (L2-hot), A-only LDS (19 KB).
__global__ __launch_bounds__(256, 4) void k_tconv(
    const float* __restrict__ in, int inStride, int Tin,
    const unsigned short* __restrict__ wsp, const float* __restrict__ bias,
    float* __restrict__ out, int outStride, int Tout,
    const float* __restrict__ bnSt, const float* __restrict__ bnG,
    const float* __restrict__ bnB, float bnCnt, float* __restrict__ statsOut) {
  __shared__ __attribute__((aligned(16))) unsigned short Ah[66 * 72];
  __shared__ __attribute__((aligned(16))) unsigned short Al[66 * 72];
  __shared__ float red[8];
  int tid = threadIdx.x;
  int ntt = (Tout + 63) >> 6;
  int tpb = NN * ntt;
  int bc = blockIdx.x / tpb, r = blockIdx.x % tpb;
  int n = r / ntt, tt = r % ntt;
  int t0 = tt << 6;
  const float* ip = in + (size_t)bc * inStride * NC + n * 64;

  float sc = 1.f, sh = 0.f;
  if (bnSt) {
    float mean = bnSt[n] / bnCnt;
    float var = bnSt[33 + n] / bnCnt - mean * mean;
    sc = rsqrtf(var + 1e-5f) * bnG[n];
    sh = bnB[n] - mean * sc;
  }
  for (int i = tid; i < 66 * 16; i += 256) {
    int row = i >> 4, c4 = i & 15;
    float4 v = make_float4(0.f, 0.f, 0.f, 0.f);
    if (t0 + row < Tin) v = *(const float4*)(ip + (size_t)(t0 + row) * NC + c4 * 4);
    if (bnSt) {
      v.x = fmaxf(v.x * sc + sh, 0.f);
      v.y = fmaxf(v.y * sc + sh, 0.f);
      v.z = fmaxf(v.z * sc + sh, 0.f);
      v.w = fmaxf(v.w * sc + sh, 0.f);
    }
    unsigned short h0 = f2bf(v.x), h1 = f2bf(v.y), h2 = f2bf(v.z), h3 = f2bf(v.w);
    unsigned short l0 = f2bf(v.x - bf2f(h0)), l1 = f2bf(v.y - bf2f(h1));
    unsigned short l2 = f2bf(v.z - bf2f(h2)), l3 = f2bf(v.w - bf2f(h3));
    uint2 ph, pl;
    ph.x = (unsigned)h0 | ((unsigned)h1 << 16); ph.y = (unsigned)h2 | ((unsigned)h3 << 16);
    pl.x = (unsigned)l0 | ((unsigned)l1 << 16); pl.y = (unsigned)l2 | ((unsigned)l3 << 16);
    *(uint2*)(Ah + row * 72 + c4 * 4) = ph;
    *(uint2*)(Al + row * 72 + c4 * 4) = pl;
  }
  __syncthreads();

  int lane = tid & 63;
  int wv = tid >> 6;          // channel quadrant
  int m15 = lane & 15, q = lane >> 4;

  f32x4 acc[4][3];            // acc[mi][gate]
  #pragma unroll
  for (int mi = 0; mi < 4; mi++)
    #pragma unroll
    for (int j = 0; j < 3; j++) acc[mi][j] = (f32x4){0.f, 0.f, 0.f, 0.f};

  #pragma unroll
  for (int s = 0; s < 6; s++) {
    int dt = s >> 1, ks = s & 1;
    const unsigned short* wdt = wsp + (size_t)dt * 24576;
    bfrag bh[3], bl[3];
    #pragma unroll
    for (int j = 0; j < 3; j++) {
      int nt = wv + 4 * j;
      const unsigned short* bp = wdt + ((ks * 12 + nt) * 2) * 512 + lane * 8;
      bh[j] = *(const bfrag*)bp;
      bl[j] = *(const bfrag*)(bp + 512);
    }
    bfrag ah[4], al[4];
    #pragma unroll
    for (int mi = 0; mi < 4; mi++) {
      int row = mi * 16 + m15 + dt;
      int off = row * 72 + ks * 32 + q * 8;
      ah[mi] = *(const bfrag*)(Ah + off);
      al[mi] = *(const bfrag*)(Al + off);
    }
    #pragma unroll
    for (int j = 0; j < 3; j++)
      #pragma unroll
      for (int mi = 0; mi < 4; mi++) {
        acc[mi][j] = __builtin_amdgcn_mfma_f32_16x16x32_bf16(ah[mi], bh[j], acc[mi][j], 0, 0, 0);
        acc[mi][j] = __builtin_amdgcn_mfma_f32_16x16x32_bf16(ah[mi], bl[j], acc[mi][j], 0, 0, 0);
        acc[mi][j] = __builtin_amdgcn_mfma_f32_16x16x32_bf16(al[mi], bh[j], acc[mi][j], 0, 0, 0);
      }
  }

  float ssum = 0.f, sq = 0.f;
  int ch = wv * 16 + m15;
  float bP = bias[ch], bQ = bias[64 + ch], bR = bias[128 + ch];
  #pragma unroll
  for (int mi = 0; mi < 4; mi++) {
    #pragma unroll
    for (int rr = 0; rr < 4; rr++) {
      int t = t0 + mi * 16 + q * 4 + rr;
      float P = acc[mi][0][rr] + bP;
      float Q = acc[mi][1][rr] + bQ;
      float Rv = acc[mi][2][rr] + bR;
      float sg = 1.f / (1.f + __expf(-Q));
      float h = fmaxf(P * sg + Rv, 0.f);
      if (t < Tout) {
        out[(size_t)(bc * outStride + t) * NC + n * 64 + ch] = h;
        ssum += h; sq += h * h;
      }
    }
  }
  if (statsOut) {
    #pragma unroll
    for (int d = 32; d > 0; d >>= 1) {
      ssum += __shfl_down(ssum, d);
      sq += __shfl_down(sq, d);
    }
    if (lane == 0) { red[wv] = ssum; red[4 + wv] = sq; }
    __syncthreads();
    if (tid == 0) {
      atomicAdd(&statsOut[n], red[0] + red[1] + red[2] + red[3]);
      atomicAdd(&statsOut[33 + n], red[4] + red[5] + red[6] + red[7]);
    }
  }
}

// =====================================================================
// K5b: BN apply + relu + mean over T (stage 2), no materialization.
__global__ __launch_bounds__(256) void k_bnmean(
    const float* __restrict__ A, int stride, int Tv,
    const float* __restrict__ st, const float* __restrict__ gg,
    const float* __restrict__ bb, float* __restrict__ mout) {
  int idx = blockIdx.x * 256 + threadIdx.x;   // 32*2112
  int p = idx % NC, b = idx / NC;
  int n = p >> 6;
  float cnt = (float)(32 * Tv * 64);
  float mean = st[n] / cnt;
  float var = st[33 + n] / cnt - mean * mean;
  float sc = rsqrtf(var + 1e-5f) * gg[n];
  float sh = bb[n] - mean * sc;
  float acc = 0.f;
  const float* ap = A + (size_t)b * stride * NC + p;
  for (int t = 0; t < Tv; t += 4) {
    acc += fmaxf(ap[(size_t)t * NC] * sc + sh, 0.f)
         + fmaxf(ap[(size_t)(t + 1) * NC] * sc + sh, 0.f)
         + fmaxf(ap[(size_t)(t + 2) * NC] * sc + sh, 0.f)
         + fmaxf(ap[(size_t)(t + 3) * NC] * sc + sh, 0.f);
  }
  mout[idx] = acc / (float)Tv;
}

// K6a: fc1 split-K.  Grid 256 = (b 32) x (ks 8); thread = out-dim d.
__global__ __launch_bounds__(256) void k_fc1(
    const float* __restrict__ meanb, const float* __restrict__ w1,
    float* __restrict__ hb) {
  int b = blockIdx.x >> 3, ks = blockIdx.x & 7;
  int d = threadIdx.x;
  const float* mp = meanb + b * NC + ks * 264;
  const float* wp = w1 + (size_t)(ks * 264) * 256 + d;
  float acc = 0.f;
  for (int k = 0; k < 264; k += 8) {
    #pragma unroll
    for (int u = 0; u < 8; u++)
      acc += mp[k + u] * wp[(size_t)(k + u) * 256];
  }
  atomicAdd(&hb[b * 256 + d], acc);
}

// K6b: relu(h+b1) then fc2.  One block per batch sample.
__global__ __launch_bounds__(256) void k_fc2(
    const float* __restrict__ hb, const float* __restrict__ b1,
    const float* __restrict__ w2, const float* __restrict__ b2,
    float* __restrict__ out) {
  __shared__ float h[256];
  int tid = threadIdx.x, b = blockIdx.x;
  h[tid] = fmaxf(hb[b * 256 + tid] + b1[tid], 0.f);
  __syncthreads();
  if (tid < 10) {
    float a = b2[tid];
    for (int k = 0; k < 256; k++) a += h[k] * w2[k * 10 + tid];
    out[b * 10 + tid] = a;
  }
}

// =====================================================================
extern "C" void kernel_launch(void* const* d_in, const int* in_sizes, int n_in,
                              void* d_out, int out_size, void* d_ws, size_t ws_size,
                              hipStream_t stream) {
  const float* x        = (const float*)d_in[0];
  const int*   ei       = (const int*)d_in[1];
  const float* s1_tc1_w = (const float*)d_in[2];
  const float* s1_tc1_b = (const float*)d_in[3];
  const float* s1_cheb_w= (const float*)d_in[4];
  const float* s1_cheb_b= (const float*)d_in[5];
  const float* s1_tc2_w = (const float*)d_in[6];
  const float* s1_tc2_b = (const float*)d_in[7];
  const float* s1_bn_g  = (const float*)d_in[8];
  const float* s1_bn_b  = (const float*)d_in[9];
  const float* s2_tc1_w = (const float*)d_in[10];
  const float* s2_tc1_b = (const float*)d_in[11];
  const float* s2_cheb_w= (const float*)d_in[12];
  const float* s2_cheb_b= (const float*)d_in[13];
  const float* s2_tc2_w = (const float*)d_in[14];
  const float* s2_tc2_b = (const float*)d_in[15];
  const float* s2_bn_g  = (const float*)d_in[16];
  const float* s2_bn_b  = (const float*)d_in[17];
  const float* fc1_w    = (const float*)d_in[18];
  const float* fc1_b    = (const float*)d_in[19];
  const float* fc2_w    = (const float*)d_in[20];
  const float* fc2_b    = (const float*)d_in[21];
  float* ws  = (float*)d_ws;
  float* out = (float*)d_out;

  int chunk = 8;
  while (chunk > 1 &&
         ((size_t)OFF_A + A_ELEMS + (size_t)chunk * SLAB * 2) * 4 > ws_size)
    chunk >>= 1;
  float* A  = ws + OFF_A;
  float* HS = A + A_ELEMS;
  float* CS = HS + (size_t)chunk * SLAB;

  hipMemsetAsync(ws + OFF_ST1, 0, (OFF_HB + 8192 - OFF_ST1) * sizeof(float), stream);
  k_prep<<<289, 256, 0, stream>>>(ei, s1_cheb_w, s2_cheb_w,
                                  s1_tc2_w, s2_tc1_w, s2_tc2_w, ws);

  const unsigned short* wt0 = (const unsigned short*)(ws + OFF_WT0);
  const unsigned short* wt1 = (const unsigned short*)(ws + OFF_WT1);
  const unsigned short* wt2 = (const unsigned short*)(ws + OFF_WT2);
  const unsigned short* uf1 = (const unsigned short*)(ws + OFF_UP1);
  const unsigned short* uf2 = (const unsigned short*)(ws + OFF_UP2);

  int nchunks = 32 / chunk;
  int rowsC = chunk * 510 * NN;
  int nblkC = (rowsC + 63) / 64;
  float cnt1 = (float)(32 * 508 * 64);
  // ---------------- stage 1 ----------------
  for (int ci = 0; ci < nchunks; ci++) {
    int b0 = ci * chunk;
    int total0 = chunk * 510 * NC;
    k_tconv0<<<(total0 + 255) / 256, 256, 0, stream>>>(x, s1_tc1_w, s1_tc1_b,
                                                       HS, b0, total0);
    k_chebmm<<<nblkC, 256, 0, stream>>>(HS, uf1, s1_cheb_b, CS, ws, rowsC);
    k_tconv<<<chunk * NN * 8, 256, 0, stream>>>(CS, 510, 510, wt0, s1_tc2_b,
                                                A + (size_t)b0 * 508 * NC, 508, 508,
                                                nullptr, nullptr, nullptr, 1.f,
                                                ws + OFF_ST1);
  }
  // ---------------- stage 2 ----------------
  for (int ci = 0; ci < nchunks; ci++) {
    int b0 = ci * chunk;
    k_tconv<<<chunk * NN * 8, 256, 0, stream>>>(A + (size_t)b0 * 508 * NC, 508, 508,
                                                wt1, s2_tc1_b, HS, 510, 506,
                                                ws + OFF_ST1, s1_bn_g, s1_bn_b, cnt1,
                                                nullptr);
    k_chebmm<<<nblkC, 256, 0, stream>>>(HS, uf2, s2_cheb_b, CS, ws, rowsC);
    k_tconv<<<chunk * NN * 8, 256, 0, stream>>>(CS, 510, 506, wt2, s2_tc2_b,
                                                A + (size_t)b0 * 508 * NC, 508, 504,
                                                nullptr, nullptr, nullptr, 1.f,
                                                ws + OFF_ST2);
  }
  k_bnmean<<<(32 * NC) / 256, 256, 0, stream>>>(A, 508, 504, ws + OFF_ST2,
                                                s2_bn_g, s2_bn_b, ws + OFF_MEAN);
  k_fc1<<<256, 256, 0, stream>>>(ws + OFF_MEAN, fc1_w, ws + OFF_HB);
  k_fc2<<<32, 256, 0, stream>>>(ws + OFF_HB, fc1_b, fc2_w, fc2_b, out);
}